// Round 19
// baseline (4929.520 us; speedup 1.0000x reference)
//
#include <hip/hip_runtime.h>

#define BB 256
#define TT 2048
#define HD 100

typedef _Float16 f16x8 __attribute__((ext_vector_type(8)));
typedef float f32x4 __attribute__((ext_vector_type(4)));
typedef _Float16 h2v __attribute__((ext_vector_type(2)));

// LDS strides (bytes)
#define A1S 272   // A tiles: [16 rows][136 halfs]
#define GSB 848   // G: [16 rows][212 u32], pair slot = type*52 + u/2

// arena offsets (bytes); role-disjoint regions overlap
//  both : Atile [0,4352) | G [4352,17920)
//  L1   : XC [17920,26112) | H1R [26112,51712)  (8 slots x 16 rows x 50 u32)
// R18 BUG: ARENA was 38912 -> ring slots 4..7 were OUT OF BOUNDS of the
// __shared__ array; OOB LDS writes are dropped / reads return 0, so half of
// every flush group reached h1buf as zeros (absmax 1.5e-2). ARENA must cover
// the full 8-slot ring: 26112 + 8*16*50*4 = 51712.
#define OFF_XC  17920
#define OFF_H1R 26112
#define ARENA   51712

__device__ __forceinline__ unsigned packh2(float a, float b) {
    h2v p; p[0] = (_Float16)a; p[1] = (_Float16)b;
    return __builtin_bit_cast(unsigned, p);
}
__device__ __forceinline__ float2 unp(unsigned u) {
    h2v p = __builtin_bit_cast(h2v, u);
    return make_float2((float)p[0], (float)p[1]);
}
__device__ __forceinline__ float rcp_f(float x) {
#if __has_builtin(__builtin_amdgcn_rcpf)
    return __builtin_amdgcn_rcpf(x);
#else
    return 1.0f / x;
#endif
}
#define LOG2E 1.4426950408889634f
__device__ __forceinline__ float tanh_f(float x) {
    return fmaf(2.0f, rcp_f(1.0f + exp2f(-2.0f * LOG2E * x)), -1.0f);
}
__device__ __forceinline__ f32x4 mfma16(uint4 a, uint4 b, f32x4 c) {
    return __builtin_amdgcn_mfma_f32_16x16x32_f16(
        __builtin_bit_cast(f16x8, a), __builtin_bit_cast(f16x8, b), c, 0, 0, 0);
}

// ============ A: MFMA recurrence pair (one launch per chunk) ============
// grid 32 x 512. blocks 0..15: L1 chunk ch; blocks 16..31: L2 chunk ch-1.
// Fragment layouts verbatim R13/R14 (verified): A row=l&15 k=(l>>4)*8+i;
// B col=l&15 same k (register/AGPR-resident, free for MFMA); C col=l&15
// row=(l>>4)*4+j. Per role ~150 regs -> no R13 cross-role spill.
// L2's input projection is PRECOMPUTED (xg2T, R16) and enters as the MFMA
// C-initializer (biases folded) -> L2 recurrence is h2.w_hh2 only (K=100pad128).
// L1 h1 output goes to an 8-slot LDS ring, flushed to h1buf every 4 steps
// (R17) -> vmcnt drain on 1/4 of barriers only.
__global__ __launch_bounds__(512, 1) void lstm_mfma_rec(
    const float* __restrict__ x,
    const float* __restrict__ w_ih1, const float* __restrict__ w_hh1,
    const float* __restrict__ b_ih1, const float* __restrict__ b_hh1,
    const float* __restrict__ w_hh2,
    const float* __restrict__ xg2T,  // [Tc][400][256] f32 (biases included)
    unsigned* __restrict__ h1buf,    // [Tc][256][52] u32 packed f16x2
    float* __restrict__ c1s,         // [256][100]
    unsigned* __restrict__ h2sp,     // [256][50]
    float* __restrict__ c2s,         // [256][100]
    float* __restrict__ h2f,         // [256][100]
    int Tc, int ch, int nch)
{
    const int role = blockIdx.x >> 4;
    const int b0   = (blockIdx.x & 15) * 16;
    const int tid  = threadIdx.x;
    const int lane = tid & 63;
    const int w    = tid >> 6;

    __shared__ __align__(16) char LB[ARENA];
    char* At = LB;                 // A tile [16][A1S]
    char* Gb = LB + 4352;          // G [16][GSB]

    const int col = lane & 15, kg = lane >> 4;
    const int abase = col * A1S + kg * 16;
    const int growb = (kg * 4) * GSB;

    const bool isUpd = tid < 208;
    const int  urow = tid & 15;
    const int  ub   = (tid >> 4) * 8;
    const int  gub  = urow * GSB + (ub >> 1) * 4;

    if (role == 0) {
        // ===================== LAYER 1 (MFMA), chunk ch =====================
        if (ch >= nch) return;
        const int t0 = ch * Tc, first = (ch == 0);
        unsigned* XCp = (unsigned*)(LB + OFF_XC);   // [2][16][16][4]
        unsigned* H1R = (unsigned*)(LB + OFF_H1R);  // [8][16][50]
        const int T1 = 3 + (w == 5);

        uint4 b1[4][4];
        float bias1v[4], am1[4], sc1[4], ad1[4]; int goff1[4];
        #pragma unroll
        for (int ti = 0; ti < 4; ++ti) if (ti < T1) {
            const int nn = (ti < 3) ? (ti * 8 + w) : 24;
            const int gate = nn * 16 + col;
            #pragma unroll
            for (int kt = 0; kt < 4; ++kt) {
                unsigned q[4];
                #pragma unroll
                for (int qq = 0; qq < 4; ++qq) {
                    const int ka = kt * 32 + kg * 8 + 2 * qq, kb = ka + 1;
                    float va = (ka < 8) ? w_ih1[gate * 8 + ka]
                             : (ka < 108 ? w_hh1[(size_t)gate * HD + ka - 8] : 0.f);
                    float vb = (kb < 8) ? w_ih1[gate * 8 + kb]
                             : (kb < 108 ? w_hh1[(size_t)gate * HD + kb - 8] : 0.f);
                    q[qq] = packh2(va, vb);
                }
                b1[ti][kt] = make_uint4(q[0], q[1], q[2], q[3]);
            }
            bias1v[ti] = b_ih1[gate] + b_hh1[gate];
            const bool tg = (gate >= 200) && (gate < 300);
            am1[ti] = tg ? 2.f : 1.f;
            sc1[ti] = tg ? (-2.f * LOG2E) : (-LOG2E);
            ad1[ti] = tg ? -1.f : 0.f;
            const int type = gate / 100, u = gate - type * 100;
            goff1[ti] = (type * 52 + (u >> 1)) * 4 + (u & 1) * 2;
        }

        float c1a[8] = {0,0,0,0,0,0,0,0};
        if (isUpd && !first) {
            #pragma unroll
            for (int q = 0; q < 4; ++q) {
                const int u0 = ub + 2 * q;
                if (u0 < 100) {
                    c1a[2*q]   = c1s[(b0 + urow) * HD + u0];
                    c1a[2*q+1] = c1s[(b0 + urow) * HD + u0 + 1];
                }
            }
        }

        for (int i = tid; i < 16 * (A1S / 4); i += 512) ((unsigned*)At)[i] = 0u;
        for (int i = tid; i < 16 * (GSB / 4); i += 512) ((unsigned*)Gb)[i] = 0u;
        __syncthreads();     // zero-fill complete before staging
        if (!first) {        // stage prev-chunk last h1 -> A k8..107
            for (int i = tid; i < 800; i += 512) {
                const int row = i / 50, pr = i - row * 50;
                *(unsigned*)(At + row * A1S + 16 + pr * 4) =
                    h1buf[((size_t)(Tc - 1) * BB + b0 + row) * 52 + pr];
            }
        }
        {   // stage x chunk 0
            const int s = (tid >> 5) & 15, xr = (tid >> 1) & 15, hq = tid & 1;
            float4 v = *(const float4*)(x + ((size_t)(b0 + xr) * TT + t0 + s) * 8 + hq * 4);
            XCp[((0 * 16 + s) * 16 + xr) * 4 + hq * 2]     = packh2(v.x, v.y);
            XCp[((0 * 16 + s) * 16 + xr) * 4 + hq * 2 + 1] = packh2(v.z, v.w);
        }
        __syncthreads();
        if (tid < 64) {      // x(t=0) -> A k0..7
            const int xr = tid >> 2, q = tid & 3;
            *(unsigned*)(At + xr * A1S + q * 4) = XCp[((0) * 16 + xr) * 4 + q];
        }
        __syncthreads();

        #pragma unroll 1
        for (int t = 0; t < Tc; ++t) {
            // ring flush: group [s0,s0+4) finished 4 steps (8 barriers) ago
            if ((t & 3) == 3 && t >= 7) {
                const int s0 = ((t >> 2) - 1) * 4;
                for (int i = tid; i < 3200; i += 512) {
                    const int s = i / 800, rem = i - s * 800;
                    const int row = rem / 50, pr = rem - row * 50;
                    h1buf[((size_t)(s0 + s) * BB + b0 + row) * 52 + pr] =
                        H1R[(((s0 + s) & 7) * 16 + row) * 50 + pr];
                }
            }
            float4 xpf = {0.f, 0.f, 0.f, 0.f};
            const bool dopf = ((t & 15) == 14) && (t + 2 < Tc);
            const int  pfc = (t + 2) >> 4;
            const int  pfs = (tid >> 5) & 15, pfr = (tid >> 1) & 15, pfh = tid & 1;
            if (dopf)
                xpf = *(const float4*)(x + ((size_t)(b0 + pfr) * TT + t0 + pfc * 16 + pfs) * 8 + pfh * 4);

            // phase A: MFMA -> act -> G
            uint4 af[4];
            #pragma unroll
            for (int kt = 0; kt < 4; ++kt)
                af[kt] = *(const uint4*)(At + abase + kt * 64);
            #pragma unroll
            for (int ti = 0; ti < 4; ++ti) if (ti < T1) {
                f32x4 acc = {0.f, 0.f, 0.f, 0.f};
                #pragma unroll
                for (int kt = 0; kt < 4; ++kt) acc = mfma16(af[kt], b1[ti][kt], acc);
                #pragma unroll
                for (int j = 0; j < 4; ++j) {
                    float v = acc[j] + bias1v[ti];
                    float a = fmaf(am1[ti], rcp_f(1.f + exp2f(sc1[ti] * v)), ad1[ti]);
                    *(_Float16*)(Gb + growb + j * GSB + goff1[ti]) = (_Float16)a;
                }
            }
            __syncthreads();

            // phase B: update c1/h1 -> A + ring; x staging
            if (isUpd) {
                const char* gp = Gb + gub;
                uint4 pi = *(const uint4*)(gp);
                uint4 pf = *(const uint4*)(gp + 208);
                uint4 pg = *(const uint4*)(gp + 416);
                uint4 po = *(const uint4*)(gp + 624);
                unsigned ai[4] = {pi.x, pi.y, pi.z, pi.w};
                unsigned afr[4] = {pf.x, pf.y, pf.z, pf.w};
                unsigned ag[4] = {pg.x, pg.y, pg.z, pg.w};
                unsigned ao[4] = {po.x, po.y, po.z, po.w};
                #pragma unroll
                for (int q = 0; q < 4; ++q) {
                    const int u0 = ub + 2 * q;
                    float2 vi = unp(ai[q]), vf = unp(afr[q]), vg = unp(ag[q]), vo = unp(ao[q]);
                    c1a[2*q]   = vf.x * c1a[2*q]   + vi.x * vg.x;
                    c1a[2*q+1] = vf.y * c1a[2*q+1] + vi.y * vg.y;
                    float h0 = vo.x * tanh_f(c1a[2*q]);
                    float h1 = vo.y * tanh_f(c1a[2*q+1]);
                    if (u0 < 100) {
                        unsigned hp = packh2(h0, h1);
                        *(unsigned*)(At + urow * A1S + 16 + u0 * 2) = hp;
                        H1R[((t & 7) * 16 + urow) * 50 + (ub >> 1) + q] = hp;
                        if (t == Tc - 1) {
                            c1s[(b0 + urow) * HD + u0]     = c1a[2*q];
                            c1s[(b0 + urow) * HD + u0 + 1] = c1a[2*q+1];
                        }
                    }
                }
            }
            if (dopf) {
                XCp[((((pfc & 1) * 16) + pfs) * 16 + pfr) * 4 + pfh * 2]     = packh2(xpf.x, xpf.y);
                XCp[((((pfc & 1) * 16) + pfs) * 16 + pfr) * 4 + pfh * 2 + 1] = packh2(xpf.z, xpf.w);
            }
            {
                const int nt = t + 1;
                if (nt < Tc && tid < 64) {
                    const int xr = tid >> 2, q = tid & 3;
                    *(unsigned*)(At + xr * A1S + q * 4) =
                        XCp[((((nt >> 4) & 1) * 16 + (nt & 15)) * 16 + xr) * 4 + q];
                }
            }
            __syncthreads();
        }
        __syncthreads();
        {   // tail flush: last 4-step group
            const int s0 = Tc - 4;
            for (int i = tid; i < 3200; i += 512) {
                const int s = i / 800, rem = i - s * 800;
                const int row = rem / 50, pr = rem - row * 50;
                h1buf[((size_t)(s0 + s) * BB + b0 + row) * 52 + pr] =
                    H1R[(((s0 + s) & 7) * 16 + row) * 50 + pr];
            }
        }
    } else {
        // ===================== LAYER 2 (MFMA), chunk ch-1 =====================
        if (ch < 1) return;
        const int first = (ch == 1), last = (ch == nch);
        const int T2 = 3 + (w == 4);

        uint4 b2[4][4];
        float am2[4], sc2[4], ad2[4]; int goff2[4], gidx[4];
        #pragma unroll
        for (int ti = 0; ti < 4; ++ti) if (ti < T2) {
            const int nn = (ti < 3) ? (ti * 8 + w) : 24;
            const int gate = nn * 16 + col;
            gidx[ti] = gate;
            #pragma unroll
            for (int kt = 0; kt < 4; ++kt) {
                unsigned q[4];
                #pragma unroll
                for (int qq = 0; qq < 4; ++qq) {
                    const int ka = kt * 32 + kg * 8 + 2 * qq, kb = ka + 1;
                    float va = (ka < 100) ? w_hh2[(size_t)gate * HD + ka] : 0.f;
                    float vb = (kb < 100) ? w_hh2[(size_t)gate * HD + kb] : 0.f;
                    q[qq] = packh2(va, vb);
                }
                b2[ti][kt] = make_uint4(q[0], q[1], q[2], q[3]);
            }
            const bool tg = (gate >= 200) && (gate < 300);
            am2[ti] = tg ? 2.f : 1.f;
            sc2[ti] = tg ? (-2.f * LOG2E) : (-LOG2E);
            ad2[ti] = tg ? -1.f : 0.f;
            const int type = gate / 100, u = gate - type * 100;
            goff2[ti] = (type * 52 + (u >> 1)) * 4 + (u & 1) * 2;
        }

        float c2a[8] = {0,0,0,0,0,0,0,0};
        if (isUpd && !first) {
            #pragma unroll
            for (int q = 0; q < 4; ++q) {
                const int u0 = ub + 2 * q;
                if (u0 < 100) {
                    c2a[2*q]   = c2s[(b0 + urow) * HD + u0];
                    c2a[2*q+1] = c2s[(b0 + urow) * HD + u0 + 1];
                }
            }
        }

        for (int i = tid; i < 16 * (A1S / 4); i += 512) ((unsigned*)At)[i] = 0u;
        for (int i = tid; i < 16 * (GSB / 4); i += 512) ((unsigned*)Gb)[i] = 0u;
        __syncthreads();
        if (!first) {        // h2 prev state -> A k0..99
            for (int i = tid; i < 800; i += 512) {
                const int row = i / 50, pr = i - row * 50;
                *(unsigned*)(At + row * A1S + pr * 4) =
                    h2sp[(size_t)(b0 + row) * 50 + pr];
            }
        }
        __syncthreads();

        // xg C-init prefetch registers (double set)
        float4 xgc[4], xgp[4];
        #pragma unroll
        for (int ti = 0; ti < 4; ++ti) if (ti < T2)
            xgc[ti] = *(const float4*)&xg2T[((size_t)0 * 400 + gidx[ti]) * 256 + b0 + kg * 4];

        #pragma unroll 1
        for (int t = 0; t < Tc; ++t) {
            const int tn = (t + 1 < Tc) ? (t + 1) : t;
            #pragma unroll
            for (int ti = 0; ti < 4; ++ti) if (ti < T2)   // prefetch next step
                xgp[ti] = *(const float4*)&xg2T[((size_t)tn * 400 + gidx[ti]) * 256 + b0 + kg * 4];

            // phase A: MFMA (C = xg2, biases included) -> act -> G
            uint4 af[4];
            #pragma unroll
            for (int kt = 0; kt < 4; ++kt)
                af[kt] = *(const uint4*)(At + abase + kt * 64);
            #pragma unroll
            for (int ti = 0; ti < 4; ++ti) if (ti < T2) {
                f32x4 acc = __builtin_bit_cast(f32x4, xgc[ti]);
                #pragma unroll
                for (int kt = 0; kt < 4; ++kt) acc = mfma16(af[kt], b2[ti][kt], acc);
                #pragma unroll
                for (int j = 0; j < 4; ++j) {
                    float a = fmaf(am2[ti], rcp_f(1.f + exp2f(sc2[ti] * acc[j])), ad2[ti]);
                    *(_Float16*)(Gb + growb + j * GSB + goff2[ti]) = (_Float16)a;
                }
            }
            __syncthreads();

            // phase B: update c2/h2 -> A
            if (isUpd) {
                const char* gp = Gb + gub;
                uint4 pi = *(const uint4*)(gp);
                uint4 pf = *(const uint4*)(gp + 208);
                uint4 pg = *(const uint4*)(gp + 416);
                uint4 po = *(const uint4*)(gp + 624);
                unsigned ai[4] = {pi.x, pi.y, pi.z, pi.w};
                unsigned afr[4] = {pf.x, pf.y, pf.z, pf.w};
                unsigned ag[4] = {pg.x, pg.y, pg.z, pg.w};
                unsigned ao[4] = {po.x, po.y, po.z, po.w};
                #pragma unroll
                for (int q = 0; q < 4; ++q) {
                    const int u0 = ub + 2 * q;
                    float2 vi = unp(ai[q]), vf = unp(afr[q]), vg = unp(ag[q]), vo = unp(ao[q]);
                    c2a[2*q]   = vf.x * c2a[2*q]   + vi.x * vg.x;
                    c2a[2*q+1] = vf.y * c2a[2*q+1] + vi.y * vg.y;
                    float h0 = vo.x * tanh_f(c2a[2*q]);
                    float h1 = vo.y * tanh_f(c2a[2*q+1]);
                    if (u0 < 100) {
                        unsigned hp = packh2(h0, h1);
                        *(unsigned*)(At + urow * A1S + u0 * 2) = hp;
                        if (t == Tc - 1) {
                            h2sp[(size_t)(b0 + urow) * 50 + (ub >> 1) + q] = hp;
                            c2s[(b0 + urow) * HD + u0]     = c2a[2*q];
                            c2s[(b0 + urow) * HD + u0 + 1] = c2a[2*q+1];
                            if (last) {
                                h2f[(size_t)(b0 + urow) * HD + u0]     = h0;
                                h2f[(size_t)(b0 + urow) * HD + u0 + 1] = h1;
                            }
                        }
                    }
                }
            }
            #pragma unroll
            for (int ti = 0; ti < 4; ++ti) if (ti < T2) xgc[ti] = xgp[ti];
            __syncthreads();
        }
    }
}

// ============ G: xg2T[t][gate][b] = (h1 . w_ih2^T + biases) (MFMA) ============
__global__ __launch_bounds__(256, 1) void xg2_gemmT(
    const unsigned* __restrict__ h1buf,  // [M][52] u32
    const float* __restrict__ w_ih2,     // [400][100] f32
    const float* __restrict__ b_ih2, const float* __restrict__ b_hh2,
    float* __restrict__ xg2T,            // [Tc][400][256] f32
    int Mrows)
{
    const int tid = threadIdx.x, lane = tid & 63, w = tid >> 6;
    const int W  = blockIdx.x * 4 + w;
    const int mt = W / 25, nt = W - mt * 25;
    if (mt * 16 >= Mrows) return;
    const int col = lane & 15, kg = lane >> 4;
    const int r    = mt * 16 + col;
    const int gate = nt * 16 + col;

    uint4 a[4];
    #pragma unroll
    for (int kt = 0; kt < 4; ++kt)
        a[kt] = *(const uint4*)&h1buf[(size_t)r * 52 + kt * 16 + kg * 4];

    uint4 bf[4];
    #pragma unroll
    for (int kt = 0; kt < 3; ++kt) {
        const float4 va = *(const float4*)&w_ih2[(size_t)gate * HD + kt * 32 + kg * 8];
        const float4 vb = *(const float4*)&w_ih2[(size_t)gate * HD + kt * 32 + kg * 8 + 4];
        bf[kt] = make_uint4(packh2(va.x, va.y), packh2(va.z, va.w),
                            packh2(vb.x, vb.y), packh2(vb.z, vb.w));
    }
    if (kg == 0) {
        const float4 va = *(const float4*)&w_ih2[(size_t)gate * HD + 96];
        bf[3] = make_uint4(packh2(va.x, va.y), packh2(va.z, va.w), 0u, 0u);
    } else {
        bf[3] = make_uint4(0u, 0u, 0u, 0u);
    }

    f32x4 acc = {0.f, 0.f, 0.f, 0.f};
    #pragma unroll
    for (int kt = 0; kt < 4; ++kt) acc = mfma16(a[kt], bf[kt], acc);

    const float bias = b_ih2[gate] + b_hh2[gate];
    const int t  = (mt * 16) / 256;
    const int bb = (mt * 16) % 256 + kg * 4;
    float4 outv = make_float4(acc[0] + bias, acc[1] + bias, acc[2] + bias, acc[3] + bias);
    *(float4*)&xg2T[((size_t)t * 400 + gate) * 256 + bb] = outv;
}

// ---------------- FC head ----------------
__global__ void fc_head(const float* __restrict__ h2,
                        const float* __restrict__ fc1_w, const float* __restrict__ fc1_b,
                        const float* __restrict__ fc2_w, const float* __restrict__ fc2_b,
                        float* __restrict__ out)
{
    const int bidx = threadIdx.x;
    const float* h = h2 + (size_t)bidx * HD;
    float hv[HD];
    #pragma unroll
    for (int kk = 0; kk < HD / 4; ++kk) {
        float4 v = *(const float4*)(h + 4 * kk);
        hv[4*kk+0] = v.x; hv[4*kk+1] = v.y; hv[4*kk+2] = v.z; hv[4*kk+3] = v.w;
    }
    float y = fc2_b[0];
    #pragma unroll
    for (int m = 0; m < 25; ++m) {
        float a = fc1_b[m];
        const float* wp = fc1_w + m * HD;
        #pragma unroll
        for (int k = 0; k < HD; ++k) a += hv[k] * wp[k];
        y += a * fc2_w[m];
    }
    out[bidx] = y;
}

extern "C" void kernel_launch(void* const* d_in, const int* in_sizes, int n_in,
                              void* d_out, int out_size, void* d_ws, size_t ws_size,
                              hipStream_t stream) {
    const float* x     = (const float*)d_in[0];
    const float* w_ih1 = (const float*)d_in[1];
    const float* w_hh1 = (const float*)d_in[2];
    const float* b_ih1 = (const float*)d_in[3];
    const float* b_hh1 = (const float*)d_in[4];
    const float* w_ih2 = (const float*)d_in[5];
    const float* w_hh2 = (const float*)d_in[6];
    const float* b_ih2 = (const float*)d_in[7];
    const float* b_hh2 = (const float*)d_in[8];
    const float* fc1_w = (const float*)d_in[9];
    const float* fc1_b = (const float*)d_in[10];
    const float* fc2_w = (const float*)d_in[11];
    const float* fc2_b = (const float*)d_in[12];
    float* out = (float*)d_out;

    int Tc = 128;   // multiple of 16, divides TT
    auto need = [](int tc) -> size_t {
        return (size_t)tc * 400 * 256 * 4            // xg2T
             + ((size_t)tc * BB * 52 + 64) * 4       // h1buf + slack
             + (size_t)BB * (HD * 3 + 50) * 4;       // c1s,c2s,h2f,h2sp
    };
    while (Tc > 16 && need(Tc) > ws_size) Tc >>= 1;
    const int nch = TT / Tc;
    const int Mrows = Tc * BB;

    float* xg2T = (float*)d_ws;
    unsigned* h1buf = (unsigned*)(xg2T + (size_t)Tc * 400 * 256);
    float* c1s = (float*)(h1buf + (size_t)Mrows * 52 + 64);
    float* c2s = c1s + (size_t)BB * HD;
    float* h2f = c2s + (size_t)BB * HD;
    unsigned* h2sp = (unsigned*)(h2f + (size_t)BB * HD);

    const int gblocks = (Mrows / 16) * 25 / 4;

    for (int ch = 0; ch < nch; ++ch) {
        lstm_mfma_rec<<<32, 512, 0, stream>>>(x, w_ih1, w_hh1, b_ih1, b_hh1, w_hh2,
                                              xg2T, h1buf, c1s, h2sp, c2s, h2f,
                                              Tc, ch, nch);
        xg2_gemmT<<<gblocks, 256, 0, stream>>>(h1buf, w_ih2, b_ih2, b_hh2,
                                               xg2T, Mrows);
    }
    lstm_mfma_rec<<<32, 512, 0, stream>>>(x, w_ih1, w_hh1, b_ih1, b_hh1, w_hh2,
                                          xg2T, h1buf, c1s, h2sp, c2s, h2f,
                                          Tc, nch, nch);
    fc_head<<<1, 256, 0, stream>>>(h2f, fc1_w, fc1_b, fc2_w, fc2_b, out);
}